// Round 1
// baseline (606.639 us; speedup 1.0000x reference)
//
#include <hip/hip_runtime.h>
#include <hip/hip_bf16.h>

typedef __attribute__((ext_vector_type(8))) short short8;
typedef __attribute__((ext_vector_type(4))) float f32x4;

#define SEQ 2048
#define DIM 3072
#define NHEAD 24
#define HDIM 128

__device__ __forceinline__ unsigned short f2bf(float f) {
  unsigned int b = __float_as_uint(f);
  b += 0x7fffu + ((b >> 16) & 1u);
  return (unsigned short)(b >> 16);
}
__device__ __forceinline__ float bf2f(unsigned short u) {
  return __uint_as_float(((unsigned int)u) << 16);
}

__device__ __forceinline__ void async16(const void* g, void* l) {
  __builtin_amdgcn_global_load_lds(
      (const __attribute__((address_space(1))) unsigned int*)g,
      (__attribute__((address_space(3))) unsigned int*)l, 16, 0, 0);
}

// ---------------- cast x (fp32 -> bf16), 8 elems/thread ----------------
__global__ void k_cvt_x(const float* __restrict__ x, unsigned short* __restrict__ xb) {
  int idx = (blockIdx.x * 256 + threadIdx.x) * 8;
  float4 a = *(const float4*)(x + idx);
  float4 b = *(const float4*)(x + idx + 4);
  short8 o;
  o[0] = (short)f2bf(a.x); o[1] = (short)f2bf(a.y);
  o[2] = (short)f2bf(a.z); o[3] = (short)f2bf(a.w);
  o[4] = (short)f2bf(b.x); o[5] = (short)f2bf(b.y);
  o[6] = (short)f2bf(b.z); o[7] = (short)f2bf(b.w);
  *(short8*)(xb + idx) = o;
}

// ---------------- transpose + cast W (K x N fp32) -> Wt (N x K bf16) ----------------
__global__ void k_transpose(const float* __restrict__ w, unsigned short* __restrict__ wt) {
  __shared__ float tile[32][33];
  int tx = threadIdx.x & 31, ty = threadIdx.x >> 5;  // ty 0..7
  int n0 = blockIdx.x * 32, k0 = blockIdx.y * 32;
#pragma unroll
  for (int i = 0; i < 4; ++i) {
    int r = ty + i * 8;
    tile[r][tx] = w[(size_t)(k0 + r) * DIM + n0 + tx];
  }
  __syncthreads();
#pragma unroll
  for (int i = 0; i < 4; ++i) {
    int r = ty + i * 8;
    wt[(size_t)(n0 + r) * DIM + k0 + tx] = f2bf(tile[tx][r]);
  }
}

// ---------------- GEMM: C(M=2048 x N=3072) = xb @ Wt^T + bias, bf16 out ----------------
// 128x128 tile, 4 waves (2x2), each wave 64x64 = 4x4 frags of 16x16, BK=32.
__global__ __launch_bounds__(256) void k_gemm(const unsigned short* __restrict__ xb,
                                              const unsigned short* __restrict__ wt,
                                              const float* __restrict__ bias,
                                              unsigned short* __restrict__ out) {
  __shared__ unsigned short As[128 * 32];
  __shared__ unsigned short Bs[128 * 32];
  int t = threadIdx.x;
  int w = t >> 6, l = t & 63;
  int wr = w >> 1, wc = w & 1;
  int lr = l & 15, kc = l >> 4;
  int bm = blockIdx.x, bn = blockIdx.y;

  f32x4 acc[4][4];
#pragma unroll
  for (int m = 0; m < 4; ++m)
#pragma unroll
    for (int n = 0; n < 4; ++n) acc[m][n] = (f32x4){0.f, 0.f, 0.f, 0.f};

  const char* aB = (const char*)xb;
  const char* bB = (const char*)wt;
  char* asmB = (char*)As;
  char* bsmB = (char*)Bs;

  for (int k0 = 0; k0 < DIM; k0 += 32) {
#pragma unroll
    for (int i = 0; i < 2; ++i) {
      int o = (t + 256 * i) * 16;
      int row = o >> 6;     // 64 bytes per row (32 bf16)
      int kb = o & 63;
      async16(aB + ((size_t)(bm * 128 + row) * DIM + k0) * 2 + kb, asmB + o);
      async16(bB + ((size_t)(bn * 128 + row) * DIM + k0) * 2 + kb, bsmB + o);
    }
    __syncthreads();
    short8 af[4], bf[4];
#pragma unroll
    for (int m = 0; m < 4; ++m)
      af[m] = *(const short8*)(asmB + (wr * 64 + m * 16 + lr) * 64 + kc * 16);
#pragma unroll
    for (int n = 0; n < 4; ++n)
      bf[n] = *(const short8*)(bsmB + (wc * 64 + n * 16 + lr) * 64 + kc * 16);
#pragma unroll
    for (int m = 0; m < 4; ++m)
#pragma unroll
      for (int n = 0; n < 4; ++n)
        acc[m][n] = __builtin_amdgcn_mfma_f32_16x16x32_bf16(af[m], bf[n], acc[m][n], 0, 0, 0);
    __syncthreads();
  }

  int lq = l >> 4;
#pragma unroll
  for (int m = 0; m < 4; ++m)
#pragma unroll
    for (int n = 0; n < 4; ++n) {
      int gcol = bn * 128 + wc * 64 + n * 16 + lr;
      float bv = bias[gcol];
#pragma unroll
      for (int i = 0; i < 4; ++i) {
        int grow = bm * 128 + wr * 64 + m * 16 + lq * 4 + i;
        out[(size_t)grow * DIM + gcol] = f2bf(acc[m][n][i] + bv);
      }
    }
}

// ---------------- RMSNorm + RoPE, in-place on bf16 (per (s,head) row of 128) ----------------
__global__ void k_normrope(unsigned short* __restrict__ qk, const float* __restrict__ cosb,
                           const float* __restrict__ sinb, const float* __restrict__ g,
                           float scale) {
  int t = threadIdx.x;
  int w = t >> 6, l = t & 63;
  int row = blockIdx.x * 4 + w;      // 0..49151
  int s_idx = row / NHEAD, head = row % NHEAD;
  size_t base = (size_t)s_idx * DIM + head * HDIM;
  unsigned int pair = *(const unsigned int*)(qk + base + 2 * l);
  float x0 = bf2f((unsigned short)(pair & 0xffffu));
  float x1 = bf2f((unsigned short)(pair >> 16));
  float ss = x0 * x0 + x1 * x1;
#pragma unroll
  for (int off = 1; off < 64; off <<= 1) ss += __shfl_xor(ss, off);
  float r = rsqrtf(ss * (1.0f / 128.0f) + 1e-6f);
  float g0 = g[2 * l], g1 = g[2 * l + 1];
  float c0 = cosb[s_idx * HDIM + 2 * l], c1 = cosb[s_idx * HDIM + 2 * l + 1];
  float s0 = sinb[s_idx * HDIM + 2 * l], s1 = sinb[s_idx * HDIM + 2 * l + 1];
  float xn0 = x0 * r * g0, xn1 = x1 * r * g1;
  float o0 = (xn0 * c0 - xn1 * s0) * scale;
  float o1 = (xn1 * c1 + xn0 * s1) * scale;
  unsigned int po = (unsigned int)f2bf(o0) | ((unsigned int)f2bf(o1) << 16);
  *(unsigned int*)(qk + base + 2 * l) = po;
}

// ---------------- Flash attention: grid (32 qtiles, 24 heads), 4 waves x 16 q-rows ----------------
__global__ __launch_bounds__(256) void k_attn(const unsigned short* __restrict__ q,
                                              const unsigned short* __restrict__ k,
                                              const unsigned short* __restrict__ v,
                                              float* __restrict__ out) {
  __shared__ unsigned short Ksm[64 * 128];   // [kv][d]
  __shared__ unsigned short Vtsm[128 * 64];  // [d][kv]
  __shared__ unsigned short Psm[4][16 * 64]; // per-wave P staging
  int t = threadIdx.x;
  int w = t >> 6, l = t & 63;
  int lr = l & 15, lq = l >> 4;
  int h = blockIdx.y, qt = blockIdx.x;
  int q0 = qt * 64 + w * 16;

  short8 qf[4];
  {
    size_t qrow = (size_t)(q0 + lr) * DIM + h * HDIM;
#pragma unroll
    for (int kc = 0; kc < 4; ++kc) qf[kc] = *(const short8*)(q + qrow + kc * 32 + lq * 8);
  }

  f32x4 o[8];
#pragma unroll
  for (int dc = 0; dc < 8; ++dc) o[dc] = (f32x4){0.f, 0.f, 0.f, 0.f};
  float m_[4] = {-1e30f, -1e30f, -1e30f, -1e30f};
  float lsum[4] = {0.f, 0.f, 0.f, 0.f};

  for (int kt = 0; kt < 32; ++kt) {
    // stage K tile (64x128) linearly
#pragma unroll
    for (int i = 0; i < 4; ++i) {
      int off = (t + 256 * i) * 16;
      int row = off >> 8;  // 256 B per row
      int cb = off & 255;
      async16((const char*)k + ((size_t)(kt * 64 + row) * DIM + h * HDIM) * 2 + cb,
              (char*)Ksm + off);
    }
    // stage V transposed: Vtsm[d][kv]
    {
      int r = t >> 4;            // 0..15
      int c8 = (t & 15) * 8;     // d-chunk
#pragma unroll
      for (int j = 0; j < 4; ++j) {
        int rr = r + 16 * j;
        short8 vv = *(const short8*)(v + (size_t)(kt * 64 + rr) * DIM + h * HDIM + c8);
#pragma unroll
        for (int jj = 0; jj < 8; ++jj)
          Vtsm[(c8 + jj) * 64 + rr] = (unsigned short)vv[jj];
      }
    }
    __syncthreads();

    // S = Q K^T  (16 x 64 per wave)
    f32x4 s[4];
#pragma unroll
    for (int c = 0; c < 4; ++c) s[c] = (f32x4){0.f, 0.f, 0.f, 0.f};
#pragma unroll
    for (int c = 0; c < 4; ++c)
#pragma unroll
      for (int kc = 0; kc < 4; ++kc) {
        short8 kf = *(const short8*)(Ksm + (c * 16 + lr) * 128 + kc * 32 + lq * 8);
        s[c] = __builtin_amdgcn_mfma_f32_16x16x32_bf16(qf[kc], kf, s[c], 0, 0, 0);
      }

    // online softmax (rows distributed: row = lq*4+i over 16-lane groups)
    float mt[4];
#pragma unroll
    for (int i = 0; i < 4; ++i) {
      float mm = fmaxf(fmaxf(s[0][i], s[1][i]), fmaxf(s[2][i], s[3][i]));
#pragma unroll
      for (int off = 1; off < 16; off <<= 1) mm = fmaxf(mm, __shfl_xor(mm, off));
      mt[i] = mm;
    }
    float corr[4];
#pragma unroll
    for (int i = 0; i < 4; ++i) {
      float mn = fmaxf(m_[i], mt[i]);
      corr[i] = __expf(m_[i] - mn);
      m_[i] = mn;
    }
#pragma unroll
    for (int c = 0; c < 4; ++c)
#pragma unroll
      for (int i = 0; i < 4; ++i) s[c][i] = __expf(s[c][i] - m_[i]);
#pragma unroll
    for (int i = 0; i < 4; ++i) {
      float rs = s[0][i] + s[1][i] + s[2][i] + s[3][i];
#pragma unroll
      for (int off = 1; off < 16; off <<= 1) rs += __shfl_xor(rs, off);
      lsum[i] = lsum[i] * corr[i] + rs;
    }
#pragma unroll
    for (int dc = 0; dc < 8; ++dc)
#pragma unroll
      for (int i = 0; i < 4; ++i) o[dc][i] *= corr[i];

    // P -> LDS (per-wave), reread as A-fragments
    unsigned short* pw = Psm[w];
#pragma unroll
    for (int c = 0; c < 4; ++c)
#pragma unroll
      for (int i = 0; i < 4; ++i)
        pw[(lq * 4 + i) * 64 + c * 16 + lr] = f2bf(s[c][i]);
    short8 pf[2];
#pragma unroll
    for (int kvc = 0; kvc < 2; ++kvc)
      pf[kvc] = *(const short8*)(pw + lr * 64 + kvc * 32 + lq * 8);

    // O += P V
#pragma unroll
    for (int dc = 0; dc < 8; ++dc)
#pragma unroll
      for (int kvc = 0; kvc < 2; ++kvc) {
        short8 vf = *(const short8*)(Vtsm + (dc * 16 + lr) * 64 + kvc * 32 + lq * 8);
        o[dc] = __builtin_amdgcn_mfma_f32_16x16x32_bf16(pf[kvc], vf, o[dc], 0, 0, 0);
      }
    __syncthreads();
  }

#pragma unroll
  for (int dc = 0; dc < 8; ++dc)
#pragma unroll
    for (int i = 0; i < 4; ++i) {
      int grow = q0 + lq * 4 + i;
      out[(size_t)grow * DIM + h * HDIM + dc * 16 + lr] = o[dc][i] / lsum[i];
    }
}

extern "C" void kernel_launch(void* const* d_in, const int* in_sizes, int n_in,
                              void* d_out, int out_size, void* d_ws, size_t ws_size,
                              hipStream_t stream) {
  const float* x = (const float*)d_in[0];
  const float* rope_cos = (const float*)d_in[1];
  const float* rope_sin = (const float*)d_in[2];
  const float* Wq = (const float*)d_in[3];
  const float* bq = (const float*)d_in[4];
  const float* Wk = (const float*)d_in[5];
  const float* bk = (const float*)d_in[6];
  const float* Wv = (const float*)d_in[7];
  const float* bv = (const float*)d_in[8];
  const float* gq = (const float*)d_in[9];
  const float* gk = (const float*)d_in[10];
  float* out = (float*)d_out;

  unsigned short* xb = (unsigned short*)d_ws;               // 2048*3072
  unsigned short* wt = xb + (size_t)SEQ * DIM;              // 3072*3072
  unsigned short* qb = wt + (size_t)DIM * DIM;              // 2048*3072
  unsigned short* kb = qb + (size_t)SEQ * DIM;
  unsigned short* vb = kb + (size_t)SEQ * DIM;

  k_cvt_x<<<3072, 256, 0, stream>>>(x, xb);

  dim3 tg(DIM / 32, DIM / 32);
  dim3 gg(SEQ / 128, DIM / 128);

  k_transpose<<<tg, 256, 0, stream>>>(Wq, wt);
  k_gemm<<<gg, 256, 0, stream>>>(xb, wt, bq, qb);
  k_transpose<<<tg, 256, 0, stream>>>(Wk, wt);
  k_gemm<<<gg, 256, 0, stream>>>(xb, wt, bk, kb);
  k_transpose<<<tg, 256, 0, stream>>>(Wv, wt);
  k_gemm<<<gg, 256, 0, stream>>>(xb, wt, bv, vb);

  k_normrope<<<SEQ * NHEAD / 4, 256, 0, stream>>>(qb, rope_cos, rope_sin, gq,
                                                  0.08838834764831845f);
  k_normrope<<<SEQ * NHEAD / 4, 256, 0, stream>>>(kb, rope_cos, rope_sin, gk, 1.0f);

  k_attn<<<dim3(SEQ / 64, NHEAD), 256, 0, stream>>>(qb, kb, vb, out);
}

// Round 2
// 369.705 us; speedup vs baseline: 1.6409x; 1.6409x over previous
//
#include <hip/hip_runtime.h>
#include <hip/hip_bf16.h>

typedef __attribute__((ext_vector_type(8))) short short8;
typedef __attribute__((ext_vector_type(4))) float f32x4;

#define SEQ 2048
#define DIM 3072
#define NHEAD 24
#define HDIM 128

__device__ __forceinline__ unsigned short f2bf(float f) {
  unsigned int b = __float_as_uint(f);
  b += 0x7fffu + ((b >> 16) & 1u);
  return (unsigned short)(b >> 16);
}
__device__ __forceinline__ float bf2f(unsigned short u) {
  return __uint_as_float(((unsigned int)u) << 16);
}

__device__ __forceinline__ void async16(const void* g, void* l) {
  __builtin_amdgcn_global_load_lds(
      (const __attribute__((address_space(1))) unsigned int*)g,
      (__attribute__((address_space(3))) unsigned int*)l, 16, 0, 0);
}

// ---------------- cast x (fp32 -> bf16), 8 elems/thread ----------------
__global__ void k_cvt_x(const float* __restrict__ x, unsigned short* __restrict__ xb) {
  int idx = (blockIdx.x * 256 + threadIdx.x) * 8;
  float4 a = *(const float4*)(x + idx);
  float4 b = *(const float4*)(x + idx + 4);
  short8 o;
  o[0] = (short)f2bf(a.x); o[1] = (short)f2bf(a.y);
  o[2] = (short)f2bf(a.z); o[3] = (short)f2bf(a.w);
  o[4] = (short)f2bf(b.x); o[5] = (short)f2bf(b.y);
  o[6] = (short)f2bf(b.z); o[7] = (short)f2bf(b.w);
  *(short8*)(xb + idx) = o;
}

// ---------------- transpose + cast W (K x N fp32) -> Wt (N x K bf16) ----------------
__global__ void k_transpose(const float* __restrict__ w, unsigned short* __restrict__ wt) {
  __shared__ float tile[32][33];
  int tx = threadIdx.x & 31, ty = threadIdx.x >> 5;  // ty 0..7
  int n0 = blockIdx.x * 32, k0 = blockIdx.y * 32;
#pragma unroll
  for (int i = 0; i < 4; ++i) {
    int r = ty + i * 8;
    tile[r][tx] = w[(size_t)(k0 + r) * DIM + n0 + tx];
  }
  __syncthreads();
#pragma unroll
  for (int i = 0; i < 4; ++i) {
    int r = ty + i * 8;
    wt[(size_t)(n0 + r) * DIM + k0 + tx] = f2bf(tile[tx][r]);
  }
}

// ---------------- transpose V (bf16): vb[s][h*128+d] -> vt[h][d][s] ----------------
__global__ void k_transpose_v(const unsigned short* __restrict__ v,
                              unsigned short* __restrict__ vt) {
  __shared__ unsigned short tile[32][33];
  int tx = threadIdx.x & 31, ty = threadIdx.x >> 5;  // 0..7
  int s0 = blockIdx.x * 32, d0 = blockIdx.y * 32, h = blockIdx.z;
#pragma unroll
  for (int i = 0; i < 4; ++i) {
    int r = ty + i * 8;
    tile[r][tx] = v[(size_t)(s0 + r) * DIM + h * HDIM + d0 + tx];
  }
  __syncthreads();
#pragma unroll
  for (int i = 0; i < 4; ++i) {
    int r = ty + i * 8;
    vt[(size_t)(h * HDIM + d0 + r) * SEQ + s0 + tx] = tile[tx][r];
  }
}

// ---------------- GEMM: C(M=2048 x N=3072) = xb @ Wt^T + bias, bf16 out ----------------
__global__ __launch_bounds__(256) void k_gemm(const unsigned short* __restrict__ xb,
                                              const unsigned short* __restrict__ wt,
                                              const float* __restrict__ bias,
                                              unsigned short* __restrict__ out) {
  __shared__ unsigned short As[128 * 32];
  __shared__ unsigned short Bs[128 * 32];
  int t = threadIdx.x;
  int w = t >> 6, l = t & 63;
  int wr = w >> 1, wc = w & 1;
  int lr = l & 15, kc = l >> 4;
  int bm = blockIdx.x, bn = blockIdx.y;

  f32x4 acc[4][4];
#pragma unroll
  for (int m = 0; m < 4; ++m)
#pragma unroll
    for (int n = 0; n < 4; ++n) acc[m][n] = (f32x4){0.f, 0.f, 0.f, 0.f};

  const char* aB = (const char*)xb;
  const char* bB = (const char*)wt;
  char* asmB = (char*)As;
  char* bsmB = (char*)Bs;

  for (int k0 = 0; k0 < DIM; k0 += 32) {
#pragma unroll
    for (int i = 0; i < 2; ++i) {
      int o = (t + 256 * i) * 16;
      int row = o >> 6;     // 64 bytes per row (32 bf16)
      int kb = o & 63;
      async16(aB + ((size_t)(bm * 128 + row) * DIM + k0) * 2 + kb, asmB + o);
      async16(bB + ((size_t)(bn * 128 + row) * DIM + k0) * 2 + kb, bsmB + o);
    }
    __syncthreads();
    short8 af[4], bf[4];
#pragma unroll
    for (int m = 0; m < 4; ++m)
      af[m] = *(const short8*)(asmB + (wr * 64 + m * 16 + lr) * 64 + kc * 16);
#pragma unroll
    for (int n = 0; n < 4; ++n)
      bf[n] = *(const short8*)(bsmB + (wc * 64 + n * 16 + lr) * 64 + kc * 16);
#pragma unroll
    for (int m = 0; m < 4; ++m)
#pragma unroll
      for (int n = 0; n < 4; ++n)
        acc[m][n] = __builtin_amdgcn_mfma_f32_16x16x32_bf16(af[m], bf[n], acc[m][n], 0, 0, 0);
    __syncthreads();
  }

  int lq = l >> 4;
#pragma unroll
  for (int m = 0; m < 4; ++m)
#pragma unroll
    for (int n = 0; n < 4; ++n) {
      int gcol = bn * 128 + wc * 64 + n * 16 + lr;
      float bv = bias[gcol];
#pragma unroll
      for (int i = 0; i < 4; ++i) {
        int grow = bm * 128 + wr * 64 + m * 16 + lq * 4 + i;
        out[(size_t)grow * DIM + gcol] = f2bf(acc[m][n][i] + bv);
      }
    }
}

// ---------------- RMSNorm + RoPE, in-place on bf16 ----------------
__global__ void k_normrope(unsigned short* __restrict__ qk, const float* __restrict__ cosb,
                           const float* __restrict__ sinb, const float* __restrict__ g,
                           float scale) {
  int t = threadIdx.x;
  int w = t >> 6, l = t & 63;
  int row = blockIdx.x * 4 + w;
  int s_idx = row / NHEAD, head = row % NHEAD;
  size_t base = (size_t)s_idx * DIM + head * HDIM;
  unsigned int pair = *(const unsigned int*)(qk + base + 2 * l);
  float x0 = bf2f((unsigned short)(pair & 0xffffu));
  float x1 = bf2f((unsigned short)(pair >> 16));
  float ss = x0 * x0 + x1 * x1;
#pragma unroll
  for (int off = 1; off < 64; off <<= 1) ss += __shfl_xor(ss, off);
  float r = rsqrtf(ss * (1.0f / 128.0f) + 1e-6f);
  float g0 = g[2 * l], g1 = g[2 * l + 1];
  float c0 = cosb[s_idx * HDIM + 2 * l], c1 = cosb[s_idx * HDIM + 2 * l + 1];
  float s0 = sinb[s_idx * HDIM + 2 * l], s1 = sinb[s_idx * HDIM + 2 * l + 1];
  float xn0 = x0 * r * g0, xn1 = x1 * r * g1;
  float o0 = (xn0 * c0 - xn1 * s0) * scale;
  float o1 = (xn1 * c1 + xn0 * s1) * scale;
  unsigned int po = (unsigned int)f2bf(o0) | ((unsigned int)f2bf(o1) << 16);
  *(unsigned int*)(qk + base + 2 * l) = po;
}

// ---------------- Flash attention ----------------
// grid: 768 blocks (XCD-swizzled -> 3 heads per XCD), 4 waves x 16 q-rows.
// K tile [64][128] bf16 and Vt tile [128][64] bf16 staged via global_load_lds
// with XOR swizzle (byte ^= (row&7)<<4) applied to the GLOBAL source address
// (linear LDS dest, per rule #21) and re-applied on the LDS read.
__global__ __launch_bounds__(256) void k_attn(const unsigned short* __restrict__ q,
                                              const unsigned short* __restrict__ k,
                                              const unsigned short* __restrict__ vt,
                                              float* __restrict__ out) {
  __shared__ unsigned short Ksm[64 * 128];    // [kv][d], swizzled
  __shared__ unsigned short Vtsm[128 * 64];   // [d][kv], swizzled
  __shared__ unsigned short Psm[4][16 * 72];  // per-wave P, padded rows (144 B, 16-aligned)
  int t = threadIdx.x;
  int w = t >> 6, l = t & 63;
  int lr = l & 15, lq = l >> 4;
  int fid = blockIdx.x;
  int logical = (fid & 7) * 96 + (fid >> 3);  // bijective: 768 = 8 * 96
  int qt = logical & 31, h = logical >> 5;
  int q0 = qt * 64 + w * 16;

  short8 qf[4];
  {
    size_t qrow = (size_t)(q0 + lr) * DIM + h * HDIM;
#pragma unroll
    for (int kc = 0; kc < 4; ++kc) qf[kc] = *(const short8*)(q + qrow + kc * 32 + lq * 8);
  }

  f32x4 o[8];
#pragma unroll
  for (int dc = 0; dc < 8; ++dc) o[dc] = (f32x4){0.f, 0.f, 0.f, 0.f};
  float m_[4] = {-1e30f, -1e30f, -1e30f, -1e30f};
  float lsum[4] = {0.f, 0.f, 0.f, 0.f};

  for (int kt = 0; kt < 32; ++kt) {
    // stage K tile [64 rows][256 B]: linear LDS dest, pre-swizzled source
#pragma unroll
    for (int i = 0; i < 4; ++i) {
      int off = (t + 256 * i) * 16;
      int row = off >> 8;
      int cb = off & 255;
      int scb = cb ^ ((row & 7) << 4);
      async16((const char*)k + ((size_t)(kt * 64 + row) * DIM + h * HDIM) * 2 + scb,
              (char*)Ksm + off);
    }
    // stage Vt tile [128 rows][128 B]
#pragma unroll
    for (int i = 0; i < 4; ++i) {
      int off = (t + 256 * i) * 16;
      int row = off >> 7;
      int cb = off & 127;
      int scb = cb ^ ((row & 7) << 4);
      async16((const char*)vt + ((size_t)(h * HDIM + row) * SEQ + kt * 64) * 2 + scb,
              (char*)Vtsm + off);
    }
    __syncthreads();

    // S = Q K^T  (16 x 64 per wave), swizzled K reads
    f32x4 s[4];
#pragma unroll
    for (int c = 0; c < 4; ++c) s[c] = (f32x4){0.f, 0.f, 0.f, 0.f};
#pragma unroll
    for (int c = 0; c < 4; ++c)
#pragma unroll
      for (int kc = 0; kc < 4; ++kc) {
        short8 kf = *(const short8*)((const char*)Ksm + (c * 16 + lr) * 256 +
                                     ((kc * 64 + lq * 16) ^ ((lr & 7) << 4)));
        s[c] = __builtin_amdgcn_mfma_f32_16x16x32_bf16(qf[kc], kf, s[c], 0, 0, 0);
      }

    // online softmax (row = lq*4+i, reduce across 16 lanes)
    float mt[4];
#pragma unroll
    for (int i = 0; i < 4; ++i) {
      float mm = fmaxf(fmaxf(s[0][i], s[1][i]), fmaxf(s[2][i], s[3][i]));
#pragma unroll
      for (int off = 1; off < 16; off <<= 1) mm = fmaxf(mm, __shfl_xor(mm, off));
      mt[i] = mm;
    }
    float corr[4];
#pragma unroll
    for (int i = 0; i < 4; ++i) {
      float mn = fmaxf(m_[i], mt[i]);
      corr[i] = __expf(m_[i] - mn);
      m_[i] = mn;
    }
#pragma unroll
    for (int c = 0; c < 4; ++c)
#pragma unroll
      for (int i = 0; i < 4; ++i) s[c][i] = __expf(s[c][i] - m_[i]);
#pragma unroll
    for (int i = 0; i < 4; ++i) {
      float rs = s[0][i] + s[1][i] + s[2][i] + s[3][i];
#pragma unroll
      for (int off = 1; off < 16; off <<= 1) rs += __shfl_xor(rs, off);
      lsum[i] = lsum[i] * corr[i] + rs;
    }
#pragma unroll
    for (int dc = 0; dc < 8; ++dc)
#pragma unroll
      for (int i = 0; i < 4; ++i) o[dc][i] *= corr[i];

    // P -> per-wave LDS (padded 72-elem rows), reread as A-fragments
    unsigned short* pw = Psm[w];
#pragma unroll
    for (int c = 0; c < 4; ++c)
#pragma unroll
      for (int i = 0; i < 4; ++i)
        pw[(lq * 4 + i) * 72 + c * 16 + lr] = f2bf(s[c][i]);
    short8 pf[2];
#pragma unroll
    for (int kvc = 0; kvc < 2; ++kvc)
      pf[kvc] = *(const short8*)(pw + lr * 72 + kvc * 32 + lq * 8);

    // O += P V, swizzled Vt reads
#pragma unroll
    for (int dc = 0; dc < 8; ++dc)
#pragma unroll
      for (int kvc = 0; kvc < 2; ++kvc) {
        short8 vf = *(const short8*)((const char*)Vtsm + (dc * 16 + lr) * 128 +
                                     ((kvc * 64 + lq * 16) ^ ((lr & 7) << 4)));
        o[dc] = __builtin_amdgcn_mfma_f32_16x16x32_bf16(pf[kvc], vf, o[dc], 0, 0, 0);
      }
    __syncthreads();
  }

#pragma unroll
  for (int dc = 0; dc < 8; ++dc)
#pragma unroll
    for (int i = 0; i < 4; ++i) {
      int grow = q0 + lq * 4 + i;
      out[(size_t)grow * DIM + h * HDIM + dc * 16 + lr] = o[dc][i] / lsum[i];
    }
}

extern "C" void kernel_launch(void* const* d_in, const int* in_sizes, int n_in,
                              void* d_out, int out_size, void* d_ws, size_t ws_size,
                              hipStream_t stream) {
  const float* x = (const float*)d_in[0];
  const float* rope_cos = (const float*)d_in[1];
  const float* rope_sin = (const float*)d_in[2];
  const float* Wq = (const float*)d_in[3];
  const float* bq = (const float*)d_in[4];
  const float* Wk = (const float*)d_in[5];
  const float* bk = (const float*)d_in[6];
  const float* Wv = (const float*)d_in[7];
  const float* bv = (const float*)d_in[8];
  const float* gq = (const float*)d_in[9];
  const float* gk = (const float*)d_in[10];
  float* out = (float*)d_out;

  unsigned short* xb = (unsigned short*)d_ws;               // 2048*3072
  unsigned short* wt = xb + (size_t)SEQ * DIM;              // 3072*3072 (reused as vt)
  unsigned short* qb = wt + (size_t)DIM * DIM;              // 2048*3072
  unsigned short* kb = qb + (size_t)SEQ * DIM;
  unsigned short* vb = kb + (size_t)SEQ * DIM;
  unsigned short* vtb = wt;  // vt: 24*128*2048 bf16 = 12.6 MB <= wt slab (18.9 MB)

  k_cvt_x<<<3072, 256, 0, stream>>>(x, xb);

  dim3 tg(DIM / 32, DIM / 32);
  dim3 gg(SEQ / 128, DIM / 128);

  k_transpose<<<tg, 256, 0, stream>>>(Wq, wt);
  k_gemm<<<gg, 256, 0, stream>>>(xb, wt, bq, qb);
  k_transpose<<<tg, 256, 0, stream>>>(Wk, wt);
  k_gemm<<<gg, 256, 0, stream>>>(xb, wt, bk, kb);
  k_transpose<<<tg, 256, 0, stream>>>(Wv, wt);
  k_gemm<<<gg, 256, 0, stream>>>(xb, wt, bv, vb);

  k_normrope<<<SEQ * NHEAD / 4, 256, 0, stream>>>(qb, rope_cos, rope_sin, gq,
                                                  0.08838834764831845f);
  k_normrope<<<SEQ * NHEAD / 4, 256, 0, stream>>>(kb, rope_cos, rope_sin, gk, 1.0f);

  // V transpose into the (now free) wt slab, then attention
  k_transpose_v<<<dim3(SEQ / 32, HDIM / 32, NHEAD), 256, 0, stream>>>(vb, vtb);
  k_attn<<<SEQ / 64 * NHEAD, 256, 0, stream>>>(qb, kb, vtb, out);
}